// Round 1
// baseline (2705.672 us; speedup 1.0000x reference)
//
#include <hip/hip_runtime.h>

#define EMBED_DIM 64

// ---------------------------------------------------------------------------
// Index-dtype detection: reference declares int64, but if the harness ran JAX
// without x64 the arrays are int32. Values are < 100000 < 2^17, so for true
// int64 (little-endian) every odd u32 word is 0. For random int32 data in
// [0, 100000) the probability all 64 odd words are zero is ~1e-320.
// flag = 1 -> int64, flag = 0 -> int32.
// ---------------------------------------------------------------------------
__global__ void detect_idx_kernel(const unsigned int* __restrict__ rows_u32,
                                  int* __restrict__ flag) {
    if (threadIdx.x == 0 && blockIdx.x == 0) {
        int nz = 0;
        for (int i = 1; i < 128; i += 2) nz += (rows_u32[i] != 0u);
        *flag = (nz == 0) ? 1 : 0;
    }
}

// ---------------------------------------------------------------------------
// Edge-parallel COO SpMV with hardware fp32 atomics.
// 16 lanes per edge; lane k handles float4 slice k of the 64-wide embedding.
// x[c] row read = 16 lanes x 16B = one coalesced 256B segment.
// ---------------------------------------------------------------------------
__global__ __launch_bounds__(256) void spmv_coo_kernel(
    const void* __restrict__ rows_p, const void* __restrict__ cols_p,
    const float* __restrict__ vals, const float* __restrict__ x,
    float* __restrict__ out, const int* __restrict__ flag_p, int n_edges) {

    const bool i64 = (*flag_p != 0);   // wave-uniform branch
    const int lane16 = threadIdx.x & 15;

    long long t      = (long long)blockIdx.x * blockDim.x + threadIdx.x;
    long long stride = (long long)gridDim.x * blockDim.x;
    long long total  = (long long)n_edges * 16;

    for (; t < total; t += stride) {
        int e = (int)(t >> 4);
        int r, c;
        if (i64) {
            r = (int)((const long long*)rows_p)[e];
            c = (int)((const long long*)cols_p)[e];
        } else {
            r = ((const int*)rows_p)[e];
            c = ((const int*)cols_p)[e];
        }
        float v = vals[e];

        float4 xv = ((const float4*)(x + (long long)c * EMBED_DIM))[lane16];
        float* o = out + (long long)r * EMBED_DIM + lane16 * 4;

        unsafeAtomicAdd(o + 0, xv.x * v);
        unsafeAtomicAdd(o + 1, xv.y * v);
        unsafeAtomicAdd(o + 2, xv.z * v);
        unsafeAtomicAdd(o + 3, xv.w * v);
    }
}

extern "C" void kernel_launch(void* const* d_in, const int* in_sizes, int n_in,
                              void* d_out, int out_size, void* d_ws, size_t ws_size,
                              hipStream_t stream) {
    const float* x    = (const float*)d_in[0];
    const void*  rows = d_in[1];
    const void*  cols = d_in[2];
    const float* vals = (const float*)d_in[3];
    float* out = (float*)d_out;
    int n_edges = in_sizes[1];

    int* flag = (int*)d_ws;

    // Harness poisons d_out with 0xAA and never re-zeros between replays:
    // we must clear the accumulator every call.
    hipMemsetAsync(d_out, 0, (size_t)out_size * sizeof(float), stream);

    detect_idx_kernel<<<1, 64, 0, stream>>>((const unsigned int*)rows, flag);

    const int block = 256;
    const int grid  = 8192;   // grid-stride; 2.1M threads, ~24 edges-slices each
    spmv_coo_kernel<<<grid, block, 0, stream>>>(rows, cols, vals, x, out,
                                                flag, n_edges);
}

// Round 2
// 731.389 us; speedup vs baseline: 3.6994x; 3.6994x over previous
//
#include <hip/hip_runtime.h>

#define EMBED_DIM 64

// ---------------------------------------------------------------------------
// Index-dtype detection (int64 vs int32), same as round 1.
// flag = 1 -> int64, flag = 0 -> int32.
// ---------------------------------------------------------------------------
__global__ void detect_idx_kernel(const unsigned int* __restrict__ rows_u32,
                                  int* __restrict__ flag) {
    if (threadIdx.x == 0 && blockIdx.x == 0) {
        int nz = 0;
        for (int i = 1; i < 128; i += 2) nz += (rows_u32[i] != 0u);
        *flag = (nz == 0) ? 1 : 0;
    }
}

__device__ __forceinline__ int load_idx(const void* p, int e, bool i64) {
    return i64 ? (int)((const long long*)p)[e] : ((const int*)p)[e];
}

// ---------------------------------------------------------------------------
// Phase 1: histogram of row indices. counts[] must be pre-zeroed (memset).
// ---------------------------------------------------------------------------
__global__ __launch_bounds__(256) void hist_kernel(
    const void* __restrict__ rows_p, int* __restrict__ counts,
    const int* __restrict__ flag_p, int n_edges) {
    const bool i64 = (*flag_p != 0);
    int stride = gridDim.x * blockDim.x;
    for (int e = blockIdx.x * blockDim.x + threadIdx.x; e < n_edges; e += stride)
        atomicAdd(&counts[load_idx(rows_p, e, i64)], 1);
}

// ---------------------------------------------------------------------------
// Phase 2: exclusive scan of counts[N] -> offs[N+1], cursor[N].
// Single 1024-thread workgroup; each thread owns a contiguous chunk.
// In-place safe: counts aliases offs (read counts[i] before writing offs[i]).
// ---------------------------------------------------------------------------
__global__ __launch_bounds__(1024) void scan_kernel(
    int* __restrict__ offs /* counts in, offsets out, N+1 */,
    int* __restrict__ cursor, int N) {
    __shared__ int tsum[1024];
    const int tid = threadIdx.x;
    const int per = (N + 1023) / 1024;
    const int lo = tid * per;
    const int hi = min(lo + per, N);

    int s = 0;
    for (int i = lo; i < hi; ++i) s += offs[i];
    tsum[tid] = s;
    __syncthreads();

    // Hillis-Steele inclusive scan over 1024 thread sums.
    for (int d = 1; d < 1024; d <<= 1) {
        int t = (tid >= d) ? tsum[tid - d] : 0;
        __syncthreads();
        tsum[tid] += t;
        __syncthreads();
    }
    int run = tsum[tid] - s;   // exclusive prefix for this thread's chunk

    for (int i = lo; i < hi; ++i) {
        int ci = offs[i];
        offs[i] = run;
        cursor[i] = run;
        run += ci;
    }
    if (tid == 1023) offs[N] = run;   // total == n_edges
}

// ---------------------------------------------------------------------------
// Phase 3: scatter edges into CSR order via per-row cursors.
// ---------------------------------------------------------------------------
__global__ __launch_bounds__(256) void scatter_kernel(
    const void* __restrict__ rows_p, const void* __restrict__ cols_p,
    const float* __restrict__ vals, int* __restrict__ cursor,
    int* __restrict__ csr_c, float* __restrict__ csr_v,
    const int* __restrict__ flag_p, int n_edges) {
    const bool i64 = (*flag_p != 0);
    int stride = gridDim.x * blockDim.x;
    for (int e = blockIdx.x * blockDim.x + threadIdx.x; e < n_edges; e += stride) {
        int r = load_idx(rows_p, e, i64);
        int c = load_idx(cols_p, e, i64);
        int pos = atomicAdd(&cursor[r], 1);
        csr_c[pos] = c;
        csr_v[pos] = vals[e];
    }
}

// ---------------------------------------------------------------------------
// Phase 4: row-parallel gather + register accumulation. 16 lanes per row,
// each lane owns one float4 slice of the 64-wide embedding. Zero atomics;
// exactly one coalesced 256B store per row. 2-deep manual pipeline for ILP.
// ---------------------------------------------------------------------------
__global__ __launch_bounds__(256) void gather_kernel(
    const int* __restrict__ offs, const int* __restrict__ csr_c,
    const float* __restrict__ csr_v, const float* __restrict__ x,
    float* __restrict__ out, int N) {
    int t = blockIdx.x * blockDim.x + threadIdx.x;
    int r = t >> 4;
    if (r >= N) return;
    const int lane = t & 15;

    int e = offs[r];
    const int e_end = offs[r + 1];
    float4 acc = {0.f, 0.f, 0.f, 0.f};

    for (; e + 2 <= e_end; e += 2) {
        int   c0 = csr_c[e],     c1 = csr_c[e + 1];
        float v0 = csr_v[e],     v1 = csr_v[e + 1];
        float4 a = ((const float4*)(x + (size_t)c0 * EMBED_DIM))[lane];
        float4 b = ((const float4*)(x + (size_t)c1 * EMBED_DIM))[lane];
        acc.x += v0 * a.x + v1 * b.x;
        acc.y += v0 * a.y + v1 * b.y;
        acc.z += v0 * a.z + v1 * b.z;
        acc.w += v0 * a.w + v1 * b.w;
    }
    if (e < e_end) {
        int c0 = csr_c[e];
        float v0 = csr_v[e];
        float4 a = ((const float4*)(x + (size_t)c0 * EMBED_DIM))[lane];
        acc.x += v0 * a.x; acc.y += v0 * a.y;
        acc.z += v0 * a.z; acc.w += v0 * a.w;
    }
    ((float4*)(out + (size_t)r * EMBED_DIM))[lane] = acc;
}

// ---------------------------------------------------------------------------
// Round-1 fallback (atomic COO) if ws_size is too small for CSR scratch.
// ---------------------------------------------------------------------------
__global__ __launch_bounds__(256) void spmv_coo_kernel(
    const void* __restrict__ rows_p, const void* __restrict__ cols_p,
    const float* __restrict__ vals, const float* __restrict__ x,
    float* __restrict__ out, const int* __restrict__ flag_p, int n_edges) {
    const bool i64 = (*flag_p != 0);
    const int lane16 = threadIdx.x & 15;
    long long t      = (long long)blockIdx.x * blockDim.x + threadIdx.x;
    long long stride = (long long)gridDim.x * blockDim.x;
    long long total  = (long long)n_edges * 16;
    for (; t < total; t += stride) {
        int e = (int)(t >> 4);
        int r = load_idx(rows_p, e, i64);
        int c = load_idx(cols_p, e, i64);
        float v = vals[e];
        float4 xv = ((const float4*)(x + (long long)c * EMBED_DIM))[lane16];
        float* o = out + (long long)r * EMBED_DIM + lane16 * 4;
        unsafeAtomicAdd(o + 0, xv.x * v);
        unsafeAtomicAdd(o + 1, xv.y * v);
        unsafeAtomicAdd(o + 2, xv.z * v);
        unsafeAtomicAdd(o + 3, xv.w * v);
    }
}

extern "C" void kernel_launch(void* const* d_in, const int* in_sizes, int n_in,
                              void* d_out, int out_size, void* d_ws, size_t ws_size,
                              hipStream_t stream) {
    const float* x    = (const float*)d_in[0];
    const void*  rows = d_in[1];
    const void*  cols = d_in[2];
    const float* vals = (const float*)d_in[3];
    float* out = (float*)d_out;
    const int E = in_sizes[1];
    const int N = out_size / EMBED_DIM;

    // Workspace layout (all 4-byte elements):
    // [0..3]    flag (+pad)
    // [4..4+N]  offs   (N+1)  -- doubles as counts during histogram
    // then      cursor (N)
    // then      csr_c  (E)
    // then      csr_v  (E floats)
    int*   base   = (int*)d_ws;
    int*   flag   = base;
    int*   offs   = base + 4;
    int*   cursor = offs + (N + 1);
    int*   csr_c  = cursor + N;
    float* csr_v  = (float*)(csr_c + E);
    const size_t needed = (size_t)(4 + (N + 1) + N + E + E) * 4;

    detect_idx_kernel<<<1, 64, 0, stream>>>((const unsigned int*)rows, flag);

    if (ws_size < needed) {
        // Fallback: atomic COO (round-1 kernel).
        hipMemsetAsync(d_out, 0, (size_t)out_size * sizeof(float), stream);
        spmv_coo_kernel<<<8192, 256, 0, stream>>>(rows, cols, vals, x, out, flag, E);
        return;
    }

    // Zero the counts region (offs). Output is fully overwritten by gather.
    hipMemsetAsync(offs, 0, (size_t)(N + 1) * sizeof(int), stream);

    const int grid_e = 2048;
    hist_kernel<<<grid_e, 256, 0, stream>>>(rows, offs, flag, E);
    scan_kernel<<<1, 1024, 0, stream>>>(offs, cursor, N);
    scatter_kernel<<<grid_e, 256, 0, stream>>>(rows, cols, vals, cursor,
                                               csr_c, csr_v, flag, E);
    const int grid_g = (N * 16 + 255) / 256;
    gather_kernel<<<grid_g, 256, 0, stream>>>(offs, csr_c, csr_v, x, out, N);
}